// Round 2
// baseline (1952.578 us; speedup 1.0000x reference)
//
#include <hip/hip_runtime.h>

constexpr int ED = 64;    // edge feature dim
constexpr int ND = 128;   // node feature dim

// native vector type for nontemporal builtins (HIP's int4 class is rejected)
typedef int iv4 __attribute__((ext_vector_type(4)));

// One wave processes FOUR edges per iteration.
// W lives in LDS (loaded once per block): Wq[k2][j] is a float4 holding
//   {W[2k2][j], W[2k2][j+64], W[2k2+1][j], W[2k2+1][j+64]}
// so lane j serves output cols j and j+64 for two consecutive k with one
// ds_read_b128. The per-edge activation x is loaded as one dwordx4 per lane
// (lane j holds x[e0 + j/16][4*(j%16) .. +3]) and broadcast via v_readlane.
//
// R1 change: software-prefetch the NEXT group's x before the 16-atomic
// drain, so the next iteration's s_waitcnt is its own load, not all
// atomic acks (vmcnt retires in order). ei loads hoisted to loop top.
// x loads are non-temporal (one-shot 410 MB stream; keep L2/L3 for `out`).
__global__ __launch_bounds__(256)
void edge_scatter_kernel(const float* __restrict__ x,
                         const float* __restrict__ W,
                         const float* __restrict__ bias,
                         const float* __restrict__ gamma,
                         const float* __restrict__ beta,
                         const int*   __restrict__ ei,
                         int E,
                         float* __restrict__ out,
                         float* __restrict__ deg)
{
    __shared__ float4 Wq[32 * 64];   // 32 KB

    // cooperative one-time load of W into LDS (paired-k, split-column layout)
    for (int t = threadIdx.x; t < 32 * 64; t += 256) {
        const int k2 = t >> 6, j = t & 63;
        const float* Wr = W + (size_t)(2 * k2) * ND;
        Wq[t] = make_float4(Wr[j], Wr[64 + j], Wr[ND + j], Wr[ND + 64 + j]);
    }
    __syncthreads();

    const int lane = threadIdx.x & 63;
    const int wid  = blockIdx.x * (blockDim.x >> 6) + (threadIdx.x >> 6);
    const int nw   = gridDim.x * (blockDim.x >> 6);

    const float b0 = bias[lane],  b1 = bias[lane + 64];
    const float g0 = gamma[lane], g1 = gamma[lane + 64];
    const float p0 = beta[lane],  p1 = beta[lane + 64];

    const int ngroups = E >> 2;
    const iv4* x4 = (const iv4*)x;

    int g = wid;
    iv4 xi = {0, 0, 0, 0};
    if (g < ngroups) {
        xi = __builtin_nontemporal_load(&x4[(size_t)g * 64 + lane]);
    }
    while (g < ngroups) {
        // ---- prefetch next group's activation BEFORE anything else ----
        const int gn = g + nw;
        const int gl = (gn < ngroups) ? gn : g;          // clamp: harmless reload
        const iv4 xin = __builtin_nontemporal_load(&x4[(size_t)gl * 64 + lane]);

        const int e0 = g << 2;

        // edge indices hoisted to iteration top (uniform -> scalar loads)
        const int sn0 = ei[e0 + 0], dn0 = ei[E + e0 + 0];
        const int sn1 = ei[e0 + 1], dn1 = ei[E + e0 + 1];
        const int sn2 = ei[e0 + 2], dn2 = ei[E + e0 + 2];
        const int sn3 = ei[e0 + 3], dn3 = ei[E + e0 + 3];

        float h00 = b0, h01 = b1, h10 = b0, h11 = b1;
        float h20 = b0, h21 = b1, h30 = b0, h31 = b1;

#pragma unroll
        for (int kq = 0; kq < 16; ++kq) {
            // k = 4*kq .. 4*kq+3
            const float4 wA = Wq[(2 * kq) * 64 + lane];      // k=4kq, 4kq+1
            const float4 wB = Wq[(2 * kq + 1) * 64 + lane];  // k=4kq+2, 4kq+3

            // edge 0
            {
                const int ls = 0 * 16 + kq;
                const float a0 = __int_as_float(__builtin_amdgcn_readlane(xi.x, ls));
                const float a1 = __int_as_float(__builtin_amdgcn_readlane(xi.y, ls));
                const float a2 = __int_as_float(__builtin_amdgcn_readlane(xi.z, ls));
                const float a3 = __int_as_float(__builtin_amdgcn_readlane(xi.w, ls));
                h00 = fmaf(a0, wA.x, h00); h01 = fmaf(a0, wA.y, h01);
                h00 = fmaf(a1, wA.z, h00); h01 = fmaf(a1, wA.w, h01);
                h00 = fmaf(a2, wB.x, h00); h01 = fmaf(a2, wB.y, h01);
                h00 = fmaf(a3, wB.z, h00); h01 = fmaf(a3, wB.w, h01);
            }
            // edge 1
            {
                const int ls = 1 * 16 + kq;
                const float a0 = __int_as_float(__builtin_amdgcn_readlane(xi.x, ls));
                const float a1 = __int_as_float(__builtin_amdgcn_readlane(xi.y, ls));
                const float a2 = __int_as_float(__builtin_amdgcn_readlane(xi.z, ls));
                const float a3 = __int_as_float(__builtin_amdgcn_readlane(xi.w, ls));
                h10 = fmaf(a0, wA.x, h10); h11 = fmaf(a0, wA.y, h11);
                h10 = fmaf(a1, wA.z, h10); h11 = fmaf(a1, wA.w, h11);
                h10 = fmaf(a2, wB.x, h10); h11 = fmaf(a2, wB.y, h11);
                h10 = fmaf(a3, wB.z, h10); h11 = fmaf(a3, wB.w, h11);
            }
            // edge 2
            {
                const int ls = 2 * 16 + kq;
                const float a0 = __int_as_float(__builtin_amdgcn_readlane(xi.x, ls));
                const float a1 = __int_as_float(__builtin_amdgcn_readlane(xi.y, ls));
                const float a2 = __int_as_float(__builtin_amdgcn_readlane(xi.z, ls));
                const float a3 = __int_as_float(__builtin_amdgcn_readlane(xi.w, ls));
                h20 = fmaf(a0, wA.x, h20); h21 = fmaf(a0, wA.y, h21);
                h20 = fmaf(a1, wA.z, h20); h21 = fmaf(a1, wA.w, h21);
                h20 = fmaf(a2, wB.x, h20); h21 = fmaf(a2, wB.y, h21);
                h20 = fmaf(a3, wB.z, h20); h21 = fmaf(a3, wB.w, h21);
            }
            // edge 3
            {
                const int ls = 3 * 16 + kq;
                const float a0 = __int_as_float(__builtin_amdgcn_readlane(xi.x, ls));
                const float a1 = __int_as_float(__builtin_amdgcn_readlane(xi.y, ls));
                const float a2 = __int_as_float(__builtin_amdgcn_readlane(xi.z, ls));
                const float a3 = __int_as_float(__builtin_amdgcn_readlane(xi.w, ls));
                h30 = fmaf(a0, wA.x, h30); h31 = fmaf(a0, wA.y, h31);
                h30 = fmaf(a1, wA.z, h30); h31 = fmaf(a1, wA.w, h31);
                h30 = fmaf(a2, wB.x, h30); h31 = fmaf(a2, wB.y, h31);
                h30 = fmaf(a3, wB.z, h30); h31 = fmaf(a3, wB.w, h31);
            }
        }

        // ReLU
        h00 = fmaxf(h00, 0.f); h01 = fmaxf(h01, 0.f);
        h10 = fmaxf(h10, 0.f); h11 = fmaxf(h11, 0.f);
        h20 = fmaxf(h20, 0.f); h21 = fmaxf(h21, 0.f);
        h30 = fmaxf(h30, 0.f); h31 = fmaxf(h31, 0.f);

        // LayerNorm: wave-wide sum/sumsq for 4 edges
        float s0 = h00 + h01, q0 = fmaf(h00, h00, h01 * h01);
        float s1 = h10 + h11, q1 = fmaf(h10, h10, h11 * h11);
        float s2 = h20 + h21, q2 = fmaf(h20, h20, h21 * h21);
        float s3 = h30 + h31, q3 = fmaf(h30, h30, h31 * h31);
#pragma unroll
        for (int m = 1; m < 64; m <<= 1) {
            s0 += __shfl_xor(s0, m, 64); q0 += __shfl_xor(q0, m, 64);
            s1 += __shfl_xor(s1, m, 64); q1 += __shfl_xor(q1, m, 64);
            s2 += __shfl_xor(s2, m, 64); q2 += __shfl_xor(q2, m, 64);
            s3 += __shfl_xor(s3, m, 64); q3 += __shfl_xor(q3, m, 64);
        }
        const float inv = 1.0f / ND;
        const float mu0 = s0 * inv, rs0 = rsqrtf(q0 * inv - mu0 * mu0 + 1e-5f);
        const float mu1 = s1 * inv, rs1 = rsqrtf(q1 * inv - mu1 * mu1 + 1e-5f);
        const float mu2 = s2 * inv, rs2 = rsqrtf(q2 * inv - mu2 * mu2 + 1e-5f);
        const float mu3 = s3 * inv, rs3 = rsqrtf(q3 * inv - mu3 * mu3 + 1e-5f);

        const float y00 = (h00 - mu0) * rs0 * g0 + p0, y01 = (h01 - mu0) * rs0 * g1 + p1;
        const float y10 = (h10 - mu1) * rs1 * g0 + p0, y11 = (h11 - mu1) * rs1 * g1 + p1;
        const float y20 = (h20 - mu2) * rs2 * g0 + p0, y21 = (h21 - mu2) * rs2 * g1 + p1;
        const float y30 = (h30 - mu3) * rs3 * g0 + p0, y31 = (h31 - mu3) * rs3 * g1 + p1;

        // 16 feature atomics issued back-to-back (single drain point).
        // The next iteration's xi was issued BEFORE these, so its waitcnt
        // does not require the atomic acks to retire.
        unsafeAtomicAdd(&out[(size_t)dn0 * ND + lane],      y00);
        unsafeAtomicAdd(&out[(size_t)dn0 * ND + 64 + lane], y01);
        unsafeAtomicAdd(&out[(size_t)sn0 * ND + lane],      y00);
        unsafeAtomicAdd(&out[(size_t)sn0 * ND + 64 + lane], y01);
        unsafeAtomicAdd(&out[(size_t)dn1 * ND + lane],      y10);
        unsafeAtomicAdd(&out[(size_t)dn1 * ND + 64 + lane], y11);
        unsafeAtomicAdd(&out[(size_t)sn1 * ND + lane],      y10);
        unsafeAtomicAdd(&out[(size_t)sn1 * ND + 64 + lane], y11);
        unsafeAtomicAdd(&out[(size_t)dn2 * ND + lane],      y20);
        unsafeAtomicAdd(&out[(size_t)dn2 * ND + 64 + lane], y21);
        unsafeAtomicAdd(&out[(size_t)sn2 * ND + lane],      y20);
        unsafeAtomicAdd(&out[(size_t)sn2 * ND + 64 + lane], y21);
        unsafeAtomicAdd(&out[(size_t)dn3 * ND + lane],      y30);
        unsafeAtomicAdd(&out[(size_t)dn3 * ND + 64 + lane], y31);
        unsafeAtomicAdd(&out[(size_t)sn3 * ND + lane],      y30);
        unsafeAtomicAdd(&out[(size_t)sn3 * ND + 64 + lane], y31);

        // degree increments: ONE atomic instruction, 8 active lanes
        int nid = dn0;
        if (lane == 1) nid = dn1;
        if (lane == 2) nid = dn2;
        if (lane == 3) nid = dn3;
        if (lane == 4) nid = sn0;
        if (lane == 5) nid = sn1;
        if (lane == 6) nid = sn2;
        if (lane == 7) nid = sn3;
        if (lane < 8) unsafeAtomicAdd(&deg[nid], 1.0f);

        xi = xin;
        g  = gn;
    }

    // tail (E not divisible by 4): single-edge path using LDS W
    for (int e = (ngroups << 2) + wid; e < E; e += nw) {
        const int xv = __float_as_int(x[(size_t)e * ED + lane]);
        float h0 = b0, h1 = b1;
#pragma unroll
        for (int kq = 0; kq < 16; ++kq) {
            const float4 wA = Wq[(2 * kq) * 64 + lane];
            const float4 wB = Wq[(2 * kq + 1) * 64 + lane];
            const float a0 = __int_as_float(__builtin_amdgcn_readlane(xv, 4 * kq + 0));
            const float a1 = __int_as_float(__builtin_amdgcn_readlane(xv, 4 * kq + 1));
            const float a2 = __int_as_float(__builtin_amdgcn_readlane(xv, 4 * kq + 2));
            const float a3 = __int_as_float(__builtin_amdgcn_readlane(xv, 4 * kq + 3));
            h0 = fmaf(a0, wA.x, h0); h1 = fmaf(a0, wA.y, h1);
            h0 = fmaf(a1, wA.z, h0); h1 = fmaf(a1, wA.w, h1);
            h0 = fmaf(a2, wB.x, h0); h1 = fmaf(a2, wB.y, h1);
            h0 = fmaf(a3, wB.z, h0); h1 = fmaf(a3, wB.w, h1);
        }
        h0 = fmaxf(h0, 0.f); h1 = fmaxf(h1, 0.f);
        float s = h0 + h1, q = fmaf(h0, h0, h1 * h1);
#pragma unroll
        for (int m = 1; m < 64; m <<= 1) {
            s += __shfl_xor(s, m, 64); q += __shfl_xor(q, m, 64);
        }
        const float mu = s / ND, rs = rsqrtf(q / ND - mu * mu + 1e-5f);
        const float y0 = (h0 - mu) * rs * g0 + p0, y1 = (h1 - mu) * rs * g1 + p1;
        const int sn = ei[e], dn = ei[E + e];
        unsafeAtomicAdd(&out[(size_t)dn * ND + lane],      y0);
        unsafeAtomicAdd(&out[(size_t)dn * ND + 64 + lane], y1);
        unsafeAtomicAdd(&out[(size_t)sn * ND + lane],      y0);
        unsafeAtomicAdd(&out[(size_t)sn * ND + 64 + lane], y1);
        if (lane == 0) unsafeAtomicAdd(&deg[dn], 1.0f);
        if (lane == 1) unsafeAtomicAdd(&deg[sn], 1.0f);
    }
}

__global__ void finalize_kernel(float4* __restrict__ out,
                                const float* __restrict__ deg,
                                int n4)
{
    const int i = blockIdx.x * blockDim.x + threadIdx.x;
    if (i < n4) {
        const float d = fmaxf(deg[i >> 5], 1.0f);   // 32 float4 per node row
        float4 v = out[i];
        v.x /= d; v.y /= d; v.z /= d; v.w /= d;
        out[i] = v;
    }
}

extern "C" void kernel_launch(void* const* d_in, const int* in_sizes, int n_in,
                              void* d_out, int out_size, void* d_ws, size_t ws_size,
                              hipStream_t stream)
{
    const float* x     = (const float*)d_in[0];
    const float* W     = (const float*)d_in[1];
    const float* bias  = (const float*)d_in[2];
    const float* gamma = (const float*)d_in[3];
    const float* beta  = (const float*)d_in[4];
    const int*   ei    = (const int*)d_in[5];

    const int E       = in_sizes[0] / ED;
    const int n_nodes = out_size / ND;

    float* out = (float*)d_out;
    float* deg = (float*)d_ws;

    (void)hipMemsetAsync(d_out, 0, (size_t)out_size * sizeof(float), stream);
    (void)hipMemsetAsync(d_ws,  0, (size_t)n_nodes * sizeof(float), stream);

    edge_scatter_kernel<<<4096, 256, 0, stream>>>(x, W, bias, gamma, beta,
                                                  ei, E, out, deg);

    finalize_kernel<<<(out_size / 4 + 255) / 256, 256, 0, stream>>>(
        (float4*)out, deg, out_size / 4);
}

// Round 3
// 1820.694 us; speedup vs baseline: 1.0724x; 1.0724x over previous
//
#include <hip/hip_runtime.h>

constexpr int ED = 64;    // edge feature dim
constexpr int ND = 128;   // node feature dim

typedef int   iv4 __attribute__((ext_vector_type(4)));
typedef float fv2 __attribute__((ext_vector_type(2)));

// ---------------------------------------------------------------------------
// Stage 1: edge transform (Linear->ReLU->LayerNorm), h[e] written to global
// workspace with plain (nontemporal) stores. Also counts endpoint degrees
// with int atomics (3.2M dword-atomics total, ~128x less than feature path).
// Wave-per-4-edges GEMM identical to the proven atomic kernel.
// ---------------------------------------------------------------------------
__global__ __launch_bounds__(256)
void transform_kernel(const float* __restrict__ x,
                      const float* __restrict__ W,
                      const float* __restrict__ bias,
                      const float* __restrict__ gamma,
                      const float* __restrict__ beta,
                      const int*   __restrict__ ei,
                      int E,
                      float* __restrict__ h,
                      unsigned* __restrict__ cnt)
{
    __shared__ float4 Wq[32 * 64];   // 32 KB

    for (int t = threadIdx.x; t < 32 * 64; t += 256) {
        const int k2 = t >> 6, j = t & 63;
        const float* Wr = W + (size_t)(2 * k2) * ND;
        Wq[t] = make_float4(Wr[j], Wr[64 + j], Wr[ND + j], Wr[ND + 64 + j]);
    }
    __syncthreads();

    const int lane = threadIdx.x & 63;
    const int wid  = blockIdx.x * (blockDim.x >> 6) + (threadIdx.x >> 6);
    const int nw   = gridDim.x * (blockDim.x >> 6);

    const float b0 = bias[lane],  b1 = bias[lane + 64];
    const float g0 = gamma[lane], g1 = gamma[lane + 64];
    const float p0 = beta[lane],  p1 = beta[lane + 64];

    const int ngroups = E >> 2;
    const iv4* x4 = (const iv4*)x;

    for (int g = wid; g < ngroups; g += nw) {
        const int e0 = g << 2;
        const iv4 xi = __builtin_nontemporal_load(&x4[(size_t)g * 64 + lane]);

        const int sn0 = ei[e0 + 0], dn0 = ei[E + e0 + 0];
        const int sn1 = ei[e0 + 1], dn1 = ei[E + e0 + 1];
        const int sn2 = ei[e0 + 2], dn2 = ei[E + e0 + 2];
        const int sn3 = ei[e0 + 3], dn3 = ei[E + e0 + 3];

        float h00 = b0, h01 = b1, h10 = b0, h11 = b1;
        float h20 = b0, h21 = b1, h30 = b0, h31 = b1;

#pragma unroll
        for (int kq = 0; kq < 16; ++kq) {
            const float4 wA = Wq[(2 * kq) * 64 + lane];
            const float4 wB = Wq[(2 * kq + 1) * 64 + lane];
            {
                const int ls = 0 * 16 + kq;
                const float a0 = __int_as_float(__builtin_amdgcn_readlane(xi.x, ls));
                const float a1 = __int_as_float(__builtin_amdgcn_readlane(xi.y, ls));
                const float a2 = __int_as_float(__builtin_amdgcn_readlane(xi.z, ls));
                const float a3 = __int_as_float(__builtin_amdgcn_readlane(xi.w, ls));
                h00 = fmaf(a0, wA.x, h00); h01 = fmaf(a0, wA.y, h01);
                h00 = fmaf(a1, wA.z, h00); h01 = fmaf(a1, wA.w, h01);
                h00 = fmaf(a2, wB.x, h00); h01 = fmaf(a2, wB.y, h01);
                h00 = fmaf(a3, wB.z, h00); h01 = fmaf(a3, wB.w, h01);
            }
            {
                const int ls = 1 * 16 + kq;
                const float a0 = __int_as_float(__builtin_amdgcn_readlane(xi.x, ls));
                const float a1 = __int_as_float(__builtin_amdgcn_readlane(xi.y, ls));
                const float a2 = __int_as_float(__builtin_amdgcn_readlane(xi.z, ls));
                const float a3 = __int_as_float(__builtin_amdgcn_readlane(xi.w, ls));
                h10 = fmaf(a0, wA.x, h10); h11 = fmaf(a0, wA.y, h11);
                h10 = fmaf(a1, wA.z, h10); h11 = fmaf(a1, wA.w, h11);
                h10 = fmaf(a2, wB.x, h10); h11 = fmaf(a2, wB.y, h11);
                h10 = fmaf(a3, wB.z, h10); h11 = fmaf(a3, wB.w, h11);
            }
            {
                const int ls = 2 * 16 + kq;
                const float a0 = __int_as_float(__builtin_amdgcn_readlane(xi.x, ls));
                const float a1 = __int_as_float(__builtin_amdgcn_readlane(xi.y, ls));
                const float a2 = __int_as_float(__builtin_amdgcn_readlane(xi.z, ls));
                const float a3 = __int_as_float(__builtin_amdgcn_readlane(xi.w, ls));
                h20 = fmaf(a0, wA.x, h20); h21 = fmaf(a0, wA.y, h21);
                h20 = fmaf(a1, wA.z, h20); h21 = fmaf(a1, wA.w, h21);
                h20 = fmaf(a2, wB.x, h20); h21 = fmaf(a2, wB.y, h21);
                h20 = fmaf(a3, wB.z, h20); h21 = fmaf(a3, wB.w, h21);
            }
            {
                const int ls = 3 * 16 + kq;
                const float a0 = __int_as_float(__builtin_amdgcn_readlane(xi.x, ls));
                const float a1 = __int_as_float(__builtin_amdgcn_readlane(xi.y, ls));
                const float a2 = __int_as_float(__builtin_amdgcn_readlane(xi.z, ls));
                const float a3 = __int_as_float(__builtin_amdgcn_readlane(xi.w, ls));
                h30 = fmaf(a0, wA.x, h30); h31 = fmaf(a0, wA.y, h31);
                h30 = fmaf(a1, wA.z, h30); h31 = fmaf(a1, wA.w, h31);
                h30 = fmaf(a2, wB.x, h30); h31 = fmaf(a2, wB.y, h31);
                h30 = fmaf(a3, wB.z, h30); h31 = fmaf(a3, wB.w, h31);
            }
        }

        h00 = fmaxf(h00, 0.f); h01 = fmaxf(h01, 0.f);
        h10 = fmaxf(h10, 0.f); h11 = fmaxf(h11, 0.f);
        h20 = fmaxf(h20, 0.f); h21 = fmaxf(h21, 0.f);
        h30 = fmaxf(h30, 0.f); h31 = fmaxf(h31, 0.f);

        float s0 = h00 + h01, q0 = fmaf(h00, h00, h01 * h01);
        float s1 = h10 + h11, q1 = fmaf(h10, h10, h11 * h11);
        float s2 = h20 + h21, q2 = fmaf(h20, h20, h21 * h21);
        float s3 = h30 + h31, q3 = fmaf(h30, h30, h31 * h31);
#pragma unroll
        for (int m = 1; m < 64; m <<= 1) {
            s0 += __shfl_xor(s0, m, 64); q0 += __shfl_xor(q0, m, 64);
            s1 += __shfl_xor(s1, m, 64); q1 += __shfl_xor(q1, m, 64);
            s2 += __shfl_xor(s2, m, 64); q2 += __shfl_xor(q2, m, 64);
            s3 += __shfl_xor(s3, m, 64); q3 += __shfl_xor(q3, m, 64);
        }
        const float inv = 1.0f / ND;
        const float mu0 = s0 * inv, rs0 = rsqrtf(q0 * inv - mu0 * mu0 + 1e-5f);
        const float mu1 = s1 * inv, rs1 = rsqrtf(q1 * inv - mu1 * mu1 + 1e-5f);
        const float mu2 = s2 * inv, rs2 = rsqrtf(q2 * inv - mu2 * mu2 + 1e-5f);
        const float mu3 = s3 * inv, rs3 = rsqrtf(q3 * inv - mu3 * mu3 + 1e-5f);

        const float y00 = (h00 - mu0) * rs0 * g0 + p0, y01 = (h01 - mu0) * rs0 * g1 + p1;
        const float y10 = (h10 - mu1) * rs1 * g0 + p0, y11 = (h11 - mu1) * rs1 * g1 + p1;
        const float y20 = (h20 - mu2) * rs2 * g0 + p0, y21 = (h21 - mu2) * rs2 * g1 + p1;
        const float y30 = (h30 - mu3) * rs3 * g0 + p0, y31 = (h31 - mu3) * rs3 * g1 + p1;

        float* hr0 = h + (size_t)(e0 + 0) * ND;
        float* hr1 = h + (size_t)(e0 + 1) * ND;
        float* hr2 = h + (size_t)(e0 + 2) * ND;
        float* hr3 = h + (size_t)(e0 + 3) * ND;
        __builtin_nontemporal_store(y00, hr0 + lane);
        __builtin_nontemporal_store(y01, hr0 + 64 + lane);
        __builtin_nontemporal_store(y10, hr1 + lane);
        __builtin_nontemporal_store(y11, hr1 + 64 + lane);
        __builtin_nontemporal_store(y20, hr2 + lane);
        __builtin_nontemporal_store(y21, hr2 + 64 + lane);
        __builtin_nontemporal_store(y30, hr3 + lane);
        __builtin_nontemporal_store(y31, hr3 + 64 + lane);

        // endpoint degree counts: ONE atomic instruction, 8 active lanes
        int nid = dn0;
        if (lane == 1) nid = dn1;
        if (lane == 2) nid = dn2;
        if (lane == 3) nid = dn3;
        if (lane == 4) nid = sn0;
        if (lane == 5) nid = sn1;
        if (lane == 6) nid = sn2;
        if (lane == 7) nid = sn3;
        if (lane < 8) atomicAdd(&cnt[nid], 1u);
    }

    // tail (E not divisible by 4)
    for (int e = (ngroups << 2) + wid; e < E; e += nw) {
        const int xv = __float_as_int(x[(size_t)e * ED + lane]);
        float h0 = b0, h1 = b1;
#pragma unroll
        for (int kq = 0; kq < 16; ++kq) {
            const float4 wA = Wq[(2 * kq) * 64 + lane];
            const float4 wB = Wq[(2 * kq + 1) * 64 + lane];
            const float a0 = __int_as_float(__builtin_amdgcn_readlane(xv, 4 * kq + 0));
            const float a1 = __int_as_float(__builtin_amdgcn_readlane(xv, 4 * kq + 1));
            const float a2 = __int_as_float(__builtin_amdgcn_readlane(xv, 4 * kq + 2));
            const float a3 = __int_as_float(__builtin_amdgcn_readlane(xv, 4 * kq + 3));
            h0 = fmaf(a0, wA.x, h0); h1 = fmaf(a0, wA.y, h1);
            h0 = fmaf(a1, wA.z, h0); h1 = fmaf(a1, wA.w, h1);
            h0 = fmaf(a2, wB.x, h0); h1 = fmaf(a2, wB.y, h1);
            h0 = fmaf(a3, wB.z, h0); h1 = fmaf(a3, wB.w, h1);
        }
        h0 = fmaxf(h0, 0.f); h1 = fmaxf(h1, 0.f);
        float s = h0 + h1, q = fmaf(h0, h0, h1 * h1);
#pragma unroll
        for (int m = 1; m < 64; m <<= 1) {
            s += __shfl_xor(s, m, 64); q += __shfl_xor(q, m, 64);
        }
        const float mu = s / ND, rs = rsqrtf(q / ND - mu * mu + 1e-5f);
        const float y0 = (h0 - mu) * rs * g0 + p0, y1 = (h1 - mu) * rs * g1 + p1;
        float* hr = h + (size_t)e * ND;
        __builtin_nontemporal_store(y0, hr + lane);
        __builtin_nontemporal_store(y1, hr + 64 + lane);
        const int sn = ei[e], dn = ei[E + e];
        if (lane == 0) atomicAdd(&cnt[dn], 1u);
        if (lane == 1) atomicAdd(&cnt[sn], 1u);
    }
}

// ---------------------------------------------------------------------------
// Stage 2: exclusive prefix sum of cnt[N] -> offs[N+1]. Single 1024-thread WG.
// ---------------------------------------------------------------------------
__global__ __launch_bounds__(1024)
void scan_kernel(const unsigned* __restrict__ cnt,
                 unsigned* __restrict__ offs,
                 int N)
{
    __shared__ unsigned part[1024];
    const int t = threadIdx.x;
    const int chunk = (N + 1023) / 1024;
    const int lo = t * chunk;
    const int hi = (lo + chunk < N) ? lo + chunk : N;

    unsigned s = 0;
    for (int i = lo; i < hi; ++i) s += cnt[i];
    part[t] = s;
    __syncthreads();

    for (int d = 1; d < 1024; d <<= 1) {
        unsigned v = (t >= d) ? part[t - d] : 0u;
        __syncthreads();
        part[t] += v;
        __syncthreads();
    }

    unsigned run = (t == 0) ? 0u : part[t - 1];
    for (int i = lo; i < hi; ++i) { offs[i] = run; run += cnt[i]; }
    if (t == 0) offs[N] = part[1023];
}

// ---------------------------------------------------------------------------
// Stage 3: fill incidence list. i in [0,2E): node = ei[i] (ei is flat
// [src(E), dst(E)]), payload = edge id.
// ---------------------------------------------------------------------------
__global__ __launch_bounds__(256)
void fill_kernel(const int* __restrict__ ei,
                 int E,
                 const unsigned* __restrict__ offs,
                 unsigned* __restrict__ cursor,
                 int* __restrict__ adj)
{
    const int E2 = 2 * E;
    for (int i = blockIdx.x * blockDim.x + threadIdx.x; i < E2;
         i += gridDim.x * blockDim.x) {
        const int n = ei[i];
        const unsigned pos = offs[n] + atomicAdd(&cursor[n], 1u);
        adj[pos] = (i < E) ? i : i - E;
    }
}

// ---------------------------------------------------------------------------
// Stage 4: gather. One wave per node: read incident h rows (512B coalesced,
// lane j holds cols 2j,2j+1), accumulate in regs, divide by degree, store.
// No atomics, no finalize pass, no out memset.
// ---------------------------------------------------------------------------
__global__ __launch_bounds__(256)
void gather_kernel(const float* __restrict__ h,
                   const unsigned* __restrict__ offs,
                   const int* __restrict__ adj,
                   float* __restrict__ out,
                   int N)
{
    const int lane = threadIdx.x & 63;
    const int w = blockIdx.x * (blockDim.x >> 6) + (threadIdx.x >> 6);
    if (w >= N) return;

    const unsigned o0 = offs[w], o1 = offs[w + 1];
    const fv2* h2 = (const fv2*)h;

    float a0 = 0.f, a1 = 0.f;
    for (unsigned base = o0; base < o1; base += 64) {
        const int m = (int)((o1 - base < 64u) ? (o1 - base) : 64u);
        int av = 0;
        if (base + (unsigned)lane < o1) av = adj[base + lane];

        int j = 0;
        for (; j + 4 <= m; j += 4) {
            const int e0 = __builtin_amdgcn_readlane(av, j + 0);
            const int e1 = __builtin_amdgcn_readlane(av, j + 1);
            const int e2 = __builtin_amdgcn_readlane(av, j + 2);
            const int e3 = __builtin_amdgcn_readlane(av, j + 3);
            const fv2 v0 = h2[(size_t)e0 * 64 + lane];
            const fv2 v1 = h2[(size_t)e1 * 64 + lane];
            const fv2 v2 = h2[(size_t)e2 * 64 + lane];
            const fv2 v3 = h2[(size_t)e3 * 64 + lane];
            a0 += v0.x + v1.x + v2.x + v3.x;
            a1 += v0.y + v1.y + v2.y + v3.y;
        }
        for (; j < m; ++j) {
            const int e = __builtin_amdgcn_readlane(av, j);
            const fv2 v = h2[(size_t)e * 64 + lane];
            a0 += v.x; a1 += v.y;
        }
    }

    const float inv = 1.0f / fmaxf((float)(o1 - o0), 1.0f);
    fv2 r; r.x = a0 * inv; r.y = a1 * inv;
    ((fv2*)out)[(size_t)w * 64 + lane] = r;
}

// ---------------------------------------------------------------------------
// Fallback: previous atomic-scatter kernel (used when workspace is too small
// to hold h + CSR). Proven correct at 1527 us.
// ---------------------------------------------------------------------------
__global__ __launch_bounds__(256)
void edge_scatter_kernel(const float* __restrict__ x,
                         const float* __restrict__ W,
                         const float* __restrict__ bias,
                         const float* __restrict__ gamma,
                         const float* __restrict__ beta,
                         const int*   __restrict__ ei,
                         int E,
                         float* __restrict__ out,
                         float* __restrict__ deg)
{
    __shared__ float4 Wq[32 * 64];
    for (int t = threadIdx.x; t < 32 * 64; t += 256) {
        const int k2 = t >> 6, j = t & 63;
        const float* Wr = W + (size_t)(2 * k2) * ND;
        Wq[t] = make_float4(Wr[j], Wr[64 + j], Wr[ND + j], Wr[ND + 64 + j]);
    }
    __syncthreads();

    const int lane = threadIdx.x & 63;
    const int wid  = blockIdx.x * (blockDim.x >> 6) + (threadIdx.x >> 6);
    const int nw   = gridDim.x * (blockDim.x >> 6);

    const float b0 = bias[lane],  b1 = bias[lane + 64];
    const float g0 = gamma[lane], g1 = gamma[lane + 64];
    const float p0 = beta[lane],  p1 = beta[lane + 64];

    const int ngroups = E >> 2;
    const iv4* x4 = (const iv4*)x;

    for (int g = wid; g < ngroups; g += nw) {
        const int e0 = g << 2;
        const iv4 xi = __builtin_nontemporal_load(&x4[(size_t)g * 64 + lane]);

        float h00 = b0, h01 = b1, h10 = b0, h11 = b1;
        float h20 = b0, h21 = b1, h30 = b0, h31 = b1;

#pragma unroll
        for (int kq = 0; kq < 16; ++kq) {
            const float4 wA = Wq[(2 * kq) * 64 + lane];
            const float4 wB = Wq[(2 * kq + 1) * 64 + lane];
            {
                const int ls = 0 * 16 + kq;
                const float a0 = __int_as_float(__builtin_amdgcn_readlane(xi.x, ls));
                const float a1 = __int_as_float(__builtin_amdgcn_readlane(xi.y, ls));
                const float a2 = __int_as_float(__builtin_amdgcn_readlane(xi.z, ls));
                const float a3 = __int_as_float(__builtin_amdgcn_readlane(xi.w, ls));
                h00 = fmaf(a0, wA.x, h00); h01 = fmaf(a0, wA.y, h01);
                h00 = fmaf(a1, wA.z, h00); h01 = fmaf(a1, wA.w, h01);
                h00 = fmaf(a2, wB.x, h00); h01 = fmaf(a2, wB.y, h01);
                h00 = fmaf(a3, wB.z, h00); h01 = fmaf(a3, wB.w, h01);
            }
            {
                const int ls = 1 * 16 + kq;
                const float a0 = __int_as_float(__builtin_amdgcn_readlane(xi.x, ls));
                const float a1 = __int_as_float(__builtin_amdgcn_readlane(xi.y, ls));
                const float a2 = __int_as_float(__builtin_amdgcn_readlane(xi.z, ls));
                const float a3 = __int_as_float(__builtin_amdgcn_readlane(xi.w, ls));
                h10 = fmaf(a0, wA.x, h10); h11 = fmaf(a0, wA.y, h11);
                h10 = fmaf(a1, wA.z, h10); h11 = fmaf(a1, wA.w, h11);
                h10 = fmaf(a2, wB.x, h10); h11 = fmaf(a2, wB.y, h11);
                h10 = fmaf(a3, wB.z, h10); h11 = fmaf(a3, wB.w, h11);
            }
            {
                const int ls = 2 * 16 + kq;
                const float a0 = __int_as_float(__builtin_amdgcn_readlane(xi.x, ls));
                const float a1 = __int_as_float(__builtin_amdgcn_readlane(xi.y, ls));
                const float a2 = __int_as_float(__builtin_amdgcn_readlane(xi.z, ls));
                const float a3 = __int_as_float(__builtin_amdgcn_readlane(xi.w, ls));
                h20 = fmaf(a0, wA.x, h20); h21 = fmaf(a0, wA.y, h21);
                h20 = fmaf(a1, wA.z, h20); h21 = fmaf(a1, wA.w, h21);
                h20 = fmaf(a2, wB.x, h20); h21 = fmaf(a2, wB.y, h21);
                h20 = fmaf(a3, wB.z, h20); h21 = fmaf(a3, wB.w, h21);
            }
            {
                const int ls = 3 * 16 + kq;
                const float a0 = __int_as_float(__builtin_amdgcn_readlane(xi.x, ls));
                const float a1 = __int_as_float(__builtin_amdgcn_readlane(xi.y, ls));
                const float a2 = __int_as_float(__builtin_amdgcn_readlane(xi.z, ls));
                const float a3 = __int_as_float(__builtin_amdgcn_readlane(xi.w, ls));
                h30 = fmaf(a0, wA.x, h30); h31 = fmaf(a0, wA.y, h31);
                h30 = fmaf(a1, wA.z, h30); h31 = fmaf(a1, wA.w, h31);
                h30 = fmaf(a2, wB.x, h30); h31 = fmaf(a2, wB.y, h31);
                h30 = fmaf(a3, wB.z, h30); h31 = fmaf(a3, wB.w, h31);
            }
        }

        h00 = fmaxf(h00, 0.f); h01 = fmaxf(h01, 0.f);
        h10 = fmaxf(h10, 0.f); h11 = fmaxf(h11, 0.f);
        h20 = fmaxf(h20, 0.f); h21 = fmaxf(h21, 0.f);
        h30 = fmaxf(h30, 0.f); h31 = fmaxf(h31, 0.f);

        float s0 = h00 + h01, q0 = fmaf(h00, h00, h01 * h01);
        float s1 = h10 + h11, q1 = fmaf(h10, h10, h11 * h11);
        float s2 = h20 + h21, q2 = fmaf(h20, h20, h21 * h21);
        float s3 = h30 + h31, q3 = fmaf(h30, h30, h31 * h31);
#pragma unroll
        for (int m = 1; m < 64; m <<= 1) {
            s0 += __shfl_xor(s0, m, 64); q0 += __shfl_xor(q0, m, 64);
            s1 += __shfl_xor(s1, m, 64); q1 += __shfl_xor(q1, m, 64);
            s2 += __shfl_xor(s2, m, 64); q2 += __shfl_xor(q2, m, 64);
            s3 += __shfl_xor(s3, m, 64); q3 += __shfl_xor(q3, m, 64);
        }
        const float inv = 1.0f / ND;
        const float mu0 = s0 * inv, rs0 = rsqrtf(q0 * inv - mu0 * mu0 + 1e-5f);
        const float mu1 = s1 * inv, rs1 = rsqrtf(q1 * inv - mu1 * mu1 + 1e-5f);
        const float mu2 = s2 * inv, rs2 = rsqrtf(q2 * inv - mu2 * mu2 + 1e-5f);
        const float mu3 = s3 * inv, rs3 = rsqrtf(q3 * inv - mu3 * mu3 + 1e-5f);

        const float y00 = (h00 - mu0) * rs0 * g0 + p0, y01 = (h01 - mu0) * rs0 * g1 + p1;
        const float y10 = (h10 - mu1) * rs1 * g0 + p0, y11 = (h11 - mu1) * rs1 * g1 + p1;
        const float y20 = (h20 - mu2) * rs2 * g0 + p0, y21 = (h21 - mu2) * rs2 * g1 + p1;
        const float y30 = (h30 - mu3) * rs3 * g0 + p0, y31 = (h31 - mu3) * rs3 * g1 + p1;

        const int sn0 = ei[e0 + 0], dn0 = ei[E + e0 + 0];
        const int sn1 = ei[e0 + 1], dn1 = ei[E + e0 + 1];
        const int sn2 = ei[e0 + 2], dn2 = ei[E + e0 + 2];
        const int sn3 = ei[e0 + 3], dn3 = ei[E + e0 + 3];

        unsafeAtomicAdd(&out[(size_t)dn0 * ND + lane],      y00);
        unsafeAtomicAdd(&out[(size_t)dn0 * ND + 64 + lane], y01);
        unsafeAtomicAdd(&out[(size_t)sn0 * ND + lane],      y00);
        unsafeAtomicAdd(&out[(size_t)sn0 * ND + 64 + lane], y01);
        unsafeAtomicAdd(&out[(size_t)dn1 * ND + lane],      y10);
        unsafeAtomicAdd(&out[(size_t)dn1 * ND + 64 + lane], y11);
        unsafeAtomicAdd(&out[(size_t)sn1 * ND + lane],      y10);
        unsafeAtomicAdd(&out[(size_t)sn1 * ND + 64 + lane], y11);
        unsafeAtomicAdd(&out[(size_t)dn2 * ND + lane],      y20);
        unsafeAtomicAdd(&out[(size_t)dn2 * ND + 64 + lane], y21);
        unsafeAtomicAdd(&out[(size_t)sn2 * ND + lane],      y20);
        unsafeAtomicAdd(&out[(size_t)sn2 * ND + 64 + lane], y21);
        unsafeAtomicAdd(&out[(size_t)dn3 * ND + lane],      y30);
        unsafeAtomicAdd(&out[(size_t)dn3 * ND + 64 + lane], y31);
        unsafeAtomicAdd(&out[(size_t)sn3 * ND + lane],      y30);
        unsafeAtomicAdd(&out[(size_t)sn3 * ND + 64 + lane], y31);

        int nid = dn0;
        if (lane == 1) nid = dn1;
        if (lane == 2) nid = dn2;
        if (lane == 3) nid = dn3;
        if (lane == 4) nid = sn0;
        if (lane == 5) nid = sn1;
        if (lane == 6) nid = sn2;
        if (lane == 7) nid = sn3;
        if (lane < 8) unsafeAtomicAdd(&deg[nid], 1.0f);
    }

    for (int e = (ngroups << 2) + wid; e < E; e += nw) {
        const int xv = __float_as_int(x[(size_t)e * ED + lane]);
        float h0 = b0, h1 = b1;
#pragma unroll
        for (int kq = 0; kq < 16; ++kq) {
            const float4 wA = Wq[(2 * kq) * 64 + lane];
            const float4 wB = Wq[(2 * kq + 1) * 64 + lane];
            const float a0 = __int_as_float(__builtin_amdgcn_readlane(xv, 4 * kq + 0));
            const float a1 = __int_as_float(__builtin_amdgcn_readlane(xv, 4 * kq + 1));
            const float a2 = __int_as_float(__builtin_amdgcn_readlane(xv, 4 * kq + 2));
            const float a3 = __int_as_float(__builtin_amdgcn_readlane(xv, 4 * kq + 3));
            h0 = fmaf(a0, wA.x, h0); h1 = fmaf(a0, wA.y, h1);
            h0 = fmaf(a1, wA.z, h0); h1 = fmaf(a1, wA.w, h1);
            h0 = fmaf(a2, wB.x, h0); h1 = fmaf(a2, wB.y, h1);
            h0 = fmaf(a3, wB.z, h0); h1 = fmaf(a3, wB.w, h1);
        }
        h0 = fmaxf(h0, 0.f); h1 = fmaxf(h1, 0.f);
        float s = h0 + h1, q = fmaf(h0, h0, h1 * h1);
#pragma unroll
        for (int m = 1; m < 64; m <<= 1) {
            s += __shfl_xor(s, m, 64); q += __shfl_xor(q, m, 64);
        }
        const float mu = s / ND, rs = rsqrtf(q / ND - mu * mu + 1e-5f);
        const float y0 = (h0 - mu) * rs * g0 + p0, y1 = (h1 - mu) * rs * g1 + p1;
        const int sn = ei[e], dn = ei[E + e];
        unsafeAtomicAdd(&out[(size_t)dn * ND + lane],      y0);
        unsafeAtomicAdd(&out[(size_t)dn * ND + 64 + lane], y1);
        unsafeAtomicAdd(&out[(size_t)sn * ND + lane],      y0);
        unsafeAtomicAdd(&out[(size_t)sn * ND + 64 + lane], y1);
        if (lane == 0) unsafeAtomicAdd(&deg[dn], 1.0f);
        if (lane == 1) unsafeAtomicAdd(&deg[sn], 1.0f);
    }
}

__global__ void finalize_kernel(float4* __restrict__ out,
                                const float* __restrict__ deg,
                                int n4)
{
    const int i = blockIdx.x * blockDim.x + threadIdx.x;
    if (i < n4) {
        const float d = fmaxf(deg[i >> 5], 1.0f);
        float4 v = out[i];
        v.x /= d; v.y /= d; v.z /= d; v.w /= d;
        out[i] = v;
    }
}

static inline size_t align_up(size_t v, size_t a) { return (v + a - 1) & ~(a - 1); }

extern "C" void kernel_launch(void* const* d_in, const int* in_sizes, int n_in,
                              void* d_out, int out_size, void* d_ws, size_t ws_size,
                              hipStream_t stream)
{
    const float* x     = (const float*)d_in[0];
    const float* W     = (const float*)d_in[1];
    const float* bias  = (const float*)d_in[2];
    const float* gamma = (const float*)d_in[3];
    const float* beta  = (const float*)d_in[4];
    const int*   ei    = (const int*)d_in[5];

    const int E = in_sizes[0] / ED;
    const int N = out_size / ND;

    // workspace layout for CSR path
    const size_t off_h    = 0;
    const size_t off_offs = align_up(off_h + (size_t)E * ND * sizeof(float), 16);
    const size_t off_cnt  = align_up(off_offs + ((size_t)N + 1) * 4, 16);
    const size_t off_cur  = align_up(off_cnt + (size_t)N * 4, 16);
    const size_t off_adj  = align_up(off_cur + (size_t)N * 4, 16);
    const size_t need     = off_adj + (size_t)2 * E * 4;

    if (ws_size >= need) {
        char* ws = (char*)d_ws;
        float*    h      = (float*)(ws + off_h);
        unsigned* offs   = (unsigned*)(ws + off_offs);
        unsigned* cnt    = (unsigned*)(ws + off_cnt);
        unsigned* cursor = (unsigned*)(ws + off_cur);
        int*      adj    = (int*)(ws + off_adj);
        float*    out    = (float*)d_out;

        (void)hipMemsetAsync(cnt,    0, (size_t)N * 4, stream);
        (void)hipMemsetAsync(cursor, 0, (size_t)N * 4, stream);

        transform_kernel<<<4096, 256, 0, stream>>>(x, W, bias, gamma, beta,
                                                   ei, E, h, cnt);
        scan_kernel<<<1, 1024, 0, stream>>>(cnt, offs, N);
        fill_kernel<<<2048, 256, 0, stream>>>(ei, E, offs, cursor, adj);
        gather_kernel<<<(N + 3) / 4, 256, 0, stream>>>(h, offs, adj, out, N);
    } else {
        // fallback: atomic-scatter path
        float* out = (float*)d_out;
        float* deg = (float*)d_ws;
        (void)hipMemsetAsync(d_out, 0, (size_t)out_size * sizeof(float), stream);
        (void)hipMemsetAsync(d_ws,  0, (size_t)N * sizeof(float), stream);
        edge_scatter_kernel<<<4096, 256, 0, stream>>>(x, W, bias, gamma, beta,
                                                      ei, E, out, deg);
        finalize_kernel<<<(out_size / 4 + 255) / 256, 256, 0, stream>>>(
            (float4*)out, deg, out_size / 4);
    }
}